// Round 1
// baseline (4115.074 us; speedup 1.0000x reference)
//
#include <hip/hip_runtime.h>
#include <hip/hip_bf16.h>
#include <math.h>

// Problem constants
#define NTOK  65536      // B*T
#define CDIM  512
#define NHEAD 8
#define HSZ   64
#define NLAYER 6
#define DFF   2048
#define VOCAB 65

typedef unsigned short u16;
typedef __attribute__((ext_vector_type(8))) __bf16 bf16x8;
typedef __attribute__((ext_vector_type(4))) float f32x4;
typedef __attribute__((ext_vector_type(8))) unsigned short ushort8;

__device__ __forceinline__ float b2f(u16 u) {
    union { unsigned int i; float f; } x; x.i = ((unsigned int)u) << 16; return x.f;
}
__device__ __forceinline__ u16 f2b(float f) {
    union { float f; unsigned int i; } x; x.f = f;
    unsigned int r = x.i + 0x7fffu + ((x.i >> 16) & 1u);   // RNE
    return (u16)(r >> 16);
}

__device__ __forceinline__ void async16(const u16* g, u16* l) {
    __builtin_amdgcn_global_load_lds(
        (const __attribute__((address_space(1))) void*)g,
        (__attribute__((address_space(3))) void*)l, 16, 0, 0);
}

// ---------------------------------------------------------------------------
// R8: 256x256 8-phase pipelined GEMM (learn_hip m201 template, plain HIP).
//   C[M x N] = A[M x K] @ Bt[N x K]^T  (bf16 in, fp32 MFMA accum)
// Techniques: T2 LDS XOR-swizzle (granule ^= row&7 -> conflict-free
// ds_read_b128), T3/T4 8-phase interleave with COUNTED vmcnt (never 0 in
// steady state), T5 s_setprio around MFMA clusters. 8 waves (2M x 4N), each
// owns 128x64 of C; BK=64; LDS = 2 bufs x (A 32K | B 32K) = 128 KiB dynamic.
// Pipeline ledger (buffer c = t&1):
//   ph0: ds A[0-3]k0k1 + B[0-1]k0k1; stage A-h0(t+1)->c^1 | MFMA j0-1,i0-3
//   ph1: ds B[2-3]k0k1;              stage A-h1(t+1)->c^1 | MFMA j2-3,i0-3
//   ph2: ds A[4-7]k0k1;              stage B-h0(t+2)->c   | MFMA j0-1,i4-7
//   ph3: stage B-h1(t+2)->c; vmcnt(4)                     | MFMA j2-3,i4-7
// Safety: B of buf c dead after ph1 trailing barrier (lgkm0 precedes MFMA
// precedes barrier); A dead after ph2; stages only target dead regions.
// vmcnt(4) at ph3 retires exactly tile t+1's 8 loads (A staged this iter,
// B staged last iter), leaves B(t+2)'s 4 in flight. Tail: vmcnt(0).
// Swizzle is both-sides (rule 21): linear global_load_lds dest + global src
// column granule = (tid&7)^(row&7); read granule = (kk*4+quad)^(r16&7).
// K accumulation order identical to R7 kernel -> bitwise-same output.
// ---------------------------------------------------------------------------
template<int JB, int IB>
__device__ __forceinline__ void mfma_quad(f32x4 (&acc)[4][8],
                                          const bf16x8 (&af)[4][2],
                                          const bf16x8 (&bf)[4][2])
{
#pragma unroll
    for (int kk = 0; kk < 2; kk++)
#pragma unroll
        for (int j = 0; j < 2; j++)
#pragma unroll
            for (int i = 0; i < 4; i++)
                acc[JB + j][IB + i] = __builtin_amdgcn_mfma_f32_16x16x32_bf16(
                    bf[JB + j][kk], af[i][kk], acc[JB + j][IB + i], 0, 0, 0);
}

template<int EPI>
__global__ __launch_bounds__(512, 2)
void gemm256(const u16* __restrict__ A, const u16* __restrict__ Bt,
             void* Cout, const float* __restrict__ bias,
             const u16* res, int K, int lda, int N, int Nout)
{
    extern __shared__ __attribute__((aligned(16))) u16 lds[];
    const int tid = threadIdx.x;

    // XCD-aware swizzle (id%8 = XCD owns whole m-stripes; grid total %8==0)
    const int Nx = gridDim.x;
    const int id = blockIdx.y * Nx + blockIdx.x;
    const int xcd = id & 7;
    const int j0 = id >> 3;
    const int mt = xcd + 8 * (j0 / Nx);
    const int nt = j0 - (j0 / Nx) * Nx;
    const int m0 = mt * 256, n0 = nt * 256;

    const int lane = tid & 63, wvv = tid >> 6;   // 8 waves
    const int wvm = wvv >> 2, wvn = wvv & 3;     // 2M x 4N
    const int r16 = lane & 15, quad = lane >> 4;
    const int gk0 = quad ^ (r16 & 7);            // swizzled granule (kk=0)
    const int g0x8 = gk0 * 8, g1x8 = (gk0 ^ 4) * 8;
    const int arow = wvm * 128 + r16;
    const int brow = wvn * 64 + r16;

    // staging: thread -> (row = srow + q*64 (+h*128), granule sg), 2 loads/half
    const int srow = tid >> 3;                   // 0..63
    const int sg = (tid & 7) ^ (srow & 7);       // inverse-swizzled global col granule
    const u16* pA = A + (size_t)(m0 + srow) * lda + sg * 8;
    const u16* pB = Bt + (size_t)(n0 + srow) * K + sg * 8;
    u16* const ldst = lds + tid * 8;
    const size_t ldaq = (size_t)64 * lda, ldah = (size_t)128 * lda;
    const size_t kq = (size_t)64 * K, kh = (size_t)128 * K;

    const int nk = K >> 6;

    f32x4 acc[4][8] = {};
    bf16x8 af[4][2], bf[4][2];

#define STAGE_A(c, kt, h) do { \
    async16(pA + ((h) ? ldah : 0) + (size_t)((kt) * 64),        ldst + (c) * 32768 + (h) * 8192); \
    async16(pA + ((h) ? ldah : 0) + ldaq + (size_t)((kt) * 64), ldst + (c) * 32768 + (h) * 8192 + 4096); } while (0)
#define STAGE_B(c, kt, h) do { \
    async16(pB + ((h) ? kh : 0) + (size_t)((kt) * 64),          ldst + (c) * 32768 + 16384 + (h) * 8192); \
    async16(pB + ((h) ? kh : 0) + kq + (size_t)((kt) * 64),     ldst + (c) * 32768 + 16384 + (h) * 8192 + 4096); } while (0)
#define LD_A4(IB0) do { _Pragma("unroll") \
    for (int i = 0; i < 4; i++) { \
        const int ro = cb + (arow + ((IB0) + i) * 16) * 64; \
        af[i][0] = *(const bf16x8*)(const void*)&lds[ro + g0x8]; \
        af[i][1] = *(const bf16x8*)(const void*)&lds[ro + g1x8]; \
    } } while (0)
#define LD_B2(JB0) do { _Pragma("unroll") \
    for (int j = 0; j < 2; j++) { \
        const int ro = cb + 16384 + (brow + ((JB0) + j) * 16) * 64; \
        bf[(JB0) + j][0] = *(const bf16x8*)(const void*)&lds[ro + g0x8]; \
        bf[(JB0) + j][1] = *(const bf16x8*)(const void*)&lds[ro + g1x8]; \
    } } while (0)
#define LGKM0() do { asm volatile("s_waitcnt lgkmcnt(0)" ::: "memory"); \
                     __builtin_amdgcn_sched_barrier(0); } while (0)

    // prologue: tile0 (A+B, 8 loads) + tile1 B (4 loads); wait tile0 only
    STAGE_A(0, 0, 0); STAGE_A(0, 0, 1);
    STAGE_B(0, 0, 0); STAGE_B(0, 0, 1);
    if (nk > 1) {
        STAGE_B(1, 1, 0); STAGE_B(1, 1, 1);
        asm volatile("s_waitcnt vmcnt(4)" ::: "memory");
    } else {
        asm volatile("s_waitcnt vmcnt(0)" ::: "memory");
    }
    __builtin_amdgcn_s_barrier();

    for (int t = 0; t < nk; ++t) {
        const int c = t & 1;
        const int cb = c * 32768;

        // ---- phase 0
        LD_A4(0);
        LD_B2(0);
        if (t + 1 < nk) STAGE_A(c ^ 1, t + 1, 0);
        __builtin_amdgcn_s_barrier();
        LGKM0();
        __builtin_amdgcn_s_setprio(1);
        mfma_quad<0, 0>(acc, af, bf);
        __builtin_amdgcn_s_setprio(0);
        __builtin_amdgcn_s_barrier();

        // ---- phase 1
        LD_B2(2);
        if (t + 1 < nk) STAGE_A(c ^ 1, t + 1, 1);
        __builtin_amdgcn_s_barrier();
        LGKM0();
        __builtin_amdgcn_s_setprio(1);
        mfma_quad<2, 0>(acc, af, bf);
        __builtin_amdgcn_s_setprio(0);
        __builtin_amdgcn_s_barrier();

        // ---- phase 2
        LD_A4(4);
        if (t + 2 < nk) STAGE_B(c, t + 2, 0);
        __builtin_amdgcn_s_barrier();
        LGKM0();
        __builtin_amdgcn_s_setprio(1);
        mfma_quad<0, 4>(acc, af, bf);
        __builtin_amdgcn_s_setprio(0);
        __builtin_amdgcn_s_barrier();

        // ---- phase 3 (counted vmcnt: the T4 lever — never 0 mid-loop)
        if (t + 2 < nk) {
            STAGE_B(c, t + 2, 1);
            asm volatile("s_waitcnt vmcnt(4)" ::: "memory");
        } else {
            asm volatile("s_waitcnt vmcnt(0)" ::: "memory");
        }
        __builtin_amdgcn_s_barrier();
        __builtin_amdgcn_s_setprio(1);
        mfma_quad<2, 4>(acc, af, bf);
        __builtin_amdgcn_s_setprio(0);
        __builtin_amdgcn_s_barrier();
    }
#undef STAGE_A
#undef STAGE_B
#undef LD_A4
#undef LD_B2
#undef LGKM0

    // epilogue (swapped layout): row = wvm*128 + i*16 + r16,
    // cols = wvn*64 + j*16 + quad*4 + r. 8B vector stores.
#pragma unroll
    for (int i = 0; i < 8; i++) {
        const int row = m0 + wvm * 128 + i * 16 + r16;
#pragma unroll
        for (int j = 0; j < 4; j++) {
            const int colb = n0 + wvn * 64 + j * 16 + quad * 4;
            float v[4];
#pragma unroll
            for (int r = 0; r < 4; r++) v[r] = acc[j][i][r];
            if (EPI == 1 || EPI == 2) {
                const f32x4 b4 = *(const f32x4*)(const void*)&bias[colb];
#pragma unroll
                for (int r = 0; r < 4; r++) v[r] += b4[r];
            }
            if (EPI == 1) {
                const uint2 rv = *(const uint2*)(const void*)&res[(size_t)row * N + colb];
                v[0] += b2f((u16)(rv.x & 0xffffu));
                v[1] += b2f((u16)(rv.x >> 16));
                v[2] += b2f((u16)(rv.y & 0xffffu));
                v[3] += b2f((u16)(rv.y >> 16));
            }
            if (EPI == 2) {
#pragma unroll
                for (int r = 0; r < 4; r++) v[r] = fmaxf(v[r], 0.f);
            }
            uint2 o;
            o.x = (unsigned)f2b(v[0]) | ((unsigned)f2b(v[1]) << 16);
            o.y = (unsigned)f2b(v[2]) | ((unsigned)f2b(v[3]) << 16);
            *(uint2*)(void*)&((u16*)Cout)[(size_t)row * N + colb] = o;
        }
    }
}

// ---------------------------------------------------------------------------
// Legacy 256x128 GEMM — kept ONLY for the LM head (N=128 doesn't tile to 256).
// EPI 3: +bias -> f32, masked col < Nout.
// ---------------------------------------------------------------------------
template<int EPI>
__global__ __launch_bounds__(512)
void gemm_bt(const u16* __restrict__ A, const u16* __restrict__ Bt,
             void* __restrict__ Cout, const float* __restrict__ bias,
             const u16* __restrict__ res, int K, int lda, int N, int Nout)
{
    __shared__ u16 lA[2 * 256 * 32];
    __shared__ u16 lB[2 * 128 * 32];
    const int tid  = threadIdx.x;

    const int Nx = gridDim.x;
    const int id = blockIdx.y * Nx + blockIdx.x;
    const int xcd = id & 7;
    const int j0  = id >> 3;
    const int mt  = xcd + 8 * (j0 / Nx);
    const int nt  = j0 - (j0 / Nx) * Nx;
    const int m0  = mt * 256;
    const int n0  = nt * 128;

    const int lane = tid & 63;
    const int wv   = tid >> 6;
    const int wr   = (wv >> 1) * 64;
    const int wc   = (wv & 1) * 64;
    const int r16  = lane & 15;
    const int quad = lane >> 4;

    f32x4 acc[4][4] = {};

    const int srow = tid >> 2, skseg = (tid & 3) * 8;
    const u16* pA  = A  + (size_t)(m0 + srow) * lda + skseg;
    const u16* pA2 = pA + (size_t)128 * lda;
    const u16* pB  = Bt + (size_t)(n0 + srow) * K + skseg;
    u16* lAt = &lA[(size_t)tid * 8];
    u16* lBt = &lB[(size_t)tid * 8];

    for (int k0 = 0; k0 < K; k0 += 64) {
        async16(pA  + k0,      lAt);
        async16(pA2 + k0,      lAt + 4096);
        async16(pA  + k0 + 32, lAt + 8192);
        async16(pA2 + k0 + 32, lAt + 12288);
        async16(pB  + k0,      lBt);
        async16(pB  + k0 + 32, lBt + 4096);
        __syncthreads();

#pragma unroll
        for (int s = 0; s < 2; s++) {
            const u16* bA = &lA[s * 8192];
            const u16* bB = &lB[s * 4096];
            bf16x8 af[4], bfr[4];
#pragma unroll
            for (int i = 0; i < 4; i++)
                af[i] = *(const bf16x8*)(const void*)&bA[(wr + i * 16 + r16) * 32 + quad * 8];
#pragma unroll
            for (int j = 0; j < 4; j++)
                bfr[j] = *(const bf16x8*)(const void*)&bB[(wc + j * 16 + r16) * 32 + quad * 8];
#pragma unroll
            for (int j = 0; j < 4; j++)
#pragma unroll
                for (int i = 0; i < 4; i++)
                    acc[j][i] = __builtin_amdgcn_mfma_f32_16x16x32_bf16(bfr[j], af[i], acc[j][i], 0, 0, 0);
        }
        __syncthreads();
    }

#pragma unroll
    for (int i = 0; i < 4; i++) {
        const int row = m0 + wr + i * 16 + r16;
#pragma unroll
        for (int j = 0; j < 4; j++) {
            const int colb = n0 + wc + j * 16 + quad * 4;
            float v[4];
#pragma unroll
            for (int r = 0; r < 4; r++) v[r] = acc[j][i][r];
            if (EPI == 3) {
#pragma unroll
                for (int r = 0; r < 4; r++) {
                    const int col = colb + r;
                    if (col < Nout)
                        ((float*)Cout)[(size_t)row * Nout + col] = v[r] + bias[col];
                }
            } else {
                uint2 o;
                o.x = (unsigned)f2b(v[0]) | ((unsigned)f2b(v[1]) << 16);
                o.y = (unsigned)f2b(v[2]) | ((unsigned)f2b(v[3]) << 16);
                *(uint2*)(void*)&((u16*)Cout)[(size_t)row * N + colb] = o;
            }
        }
    }
}

// ---------------------------------------------------------------------------
// Attention: one wave per (b,h). T=8, HS=64. qkv layout [token][q|k|v, h*64+d].
// IN-PLACE into q-slot. NOTE: reference scale = C^-0.5 = 512^-0.5.
// ---------------------------------------------------------------------------
__global__ __launch_bounds__(256)
void attn_k(u16* __restrict__ qkv)
{
    __shared__ float sq[4][8][65], sk[4][8][65], sv[4][8][65], sp[4][64];
    const int w = threadIdx.x >> 6, lane = threadIdx.x & 63;
    const int unit = blockIdx.x * 4 + w;
    const int b = unit >> 3, h = unit & 7;
    const size_t base = (size_t)b * 8 * 1536 + h * 64;
    {
        const int t = lane >> 3, d0 = (lane & 7) * 8;
        const ushort8 q8 = *(const ushort8*)(const void*)&qkv[base + t * 1536 + d0];
        const ushort8 k8 = *(const ushort8*)(const void*)&qkv[base + t * 1536 + 512 + d0];
        const ushort8 v8 = *(const ushort8*)(const void*)&qkv[base + t * 1536 + 1024 + d0];
#pragma unroll
        for (int i = 0; i < 8; i++) {
            sq[w][t][d0 + i] = b2f(q8[i]);
            sk[w][t][d0 + i] = b2f(k8[i]);
            sv[w][t][d0 + i] = b2f(v8[i]);
        }
    }
    __syncthreads();
    const int t = lane >> 3, s = lane & 7;
    float sc = -1e30f;
    if (s <= t) {
        float d = 0.f;
#pragma unroll
        for (int c = 0; c < 64; c++) d += sq[w][t][c] * sk[w][s][c];
        sc = d * 0.04419417382415922f;          // 512^-0.5
    }
    float mx = sc;
#pragma unroll
    for (int m = 1; m < 8; m <<= 1) mx = fmaxf(mx, __shfl_xor(mx, m, 8));
    float e = __expf(sc - mx);
    if (s > t) e = 0.f;
    float sum = e;
#pragma unroll
    for (int m = 1; m < 8; m <<= 1) sum += __shfl_xor(sum, m, 8);
    sp[w][lane] = e / sum;
    __syncthreads();
    {
        const int tt = lane >> 3, d0 = (lane & 7) * 8;
        float a[8] = {};
#pragma unroll
        for (int ss = 0; ss < 8; ss++) {
            const float p = sp[w][tt * 8 + ss];
#pragma unroll
            for (int i = 0; i < 8; i++) a[i] += p * sv[w][ss][d0 + i];
        }
        ushort8 o;
#pragma unroll
        for (int i = 0; i < 8; i++) o[i] = f2b(a[i]);
        *(ushort8*)(void*)&qkv[base + tt * 1536 + d0] = o;
    }
}

// ---------------------------------------------------------------------------
// LayerNorm: wave per token, 8 elems/lane, shuffle reduction. In-place OK.
// ---------------------------------------------------------------------------
__global__ __launch_bounds__(256)
void ln_k(const u16* __restrict__ y, const float* __restrict__ g,
          const float* __restrict__ be, u16* __restrict__ x)
{
    const int w = threadIdx.x >> 6, lane = threadIdx.x & 63;
    const size_t tok = (size_t)blockIdx.x * 4 + w;
    const u16* row = y + tok * 512 + lane * 8;
    ushort8 raw = *(const ushort8*)(const void*)row;
    float v[8];
#pragma unroll
    for (int i = 0; i < 8; i++) v[i] = b2f(raw[i]);
    float s = 0.f;
#pragma unroll
    for (int i = 0; i < 8; i++) s += v[i];
#pragma unroll
    for (int m = 1; m < 64; m <<= 1) s += __shfl_xor(s, m, 64);
    const float mu = s * (1.f / 512.f);
    float q = 0.f;
#pragma unroll
    for (int i = 0; i < 8; i++) { float d = v[i] - mu; q += d * d; }
#pragma unroll
    for (int m = 1; m < 64; m <<= 1) q += __shfl_xor(q, m, 64);
    const float inv = rsqrtf(q * (1.f / 512.f) + 1e-5f);
    f32x4 g0  = *(const f32x4*)(const void*)&g[lane * 8];
    f32x4 g1  = *(const f32x4*)(const void*)&g[lane * 8 + 4];
    f32x4 b0  = *(const f32x4*)(const void*)&be[lane * 8];
    f32x4 b1v = *(const f32x4*)(const void*)&be[lane * 8 + 4];
    ushort8 o;
#pragma unroll
    for (int i = 0; i < 4; i++) o[i]     = f2b((v[i] - mu) * inv * g0[i] + b0[i]);
#pragma unroll
    for (int i = 0; i < 4; i++) o[i + 4] = f2b((v[i + 4] - mu) * inv * g1[i] + b1v[i]);
    *(ushort8*)(void*)&x[tok * 512 + lane * 8] = o;
}

// ---------------------------------------------------------------------------
// Embedding: vectorized. thread -> (token, 8-col segment).
// ---------------------------------------------------------------------------
__global__ __launch_bounds__(256)
void embed_k(const int* __restrict__ idx, const float* __restrict__ tokt,
             const float* __restrict__ pos, u16* __restrict__ xb)
{
    const int gid = blockIdx.x * 256 + threadIdx.x;
    const int tk = gid >> 6, seg = (gid & 63) * 8;
    const int t = tk & 7;
    const int ix = idx[tk];
    const f32x4 a0 = *(const f32x4*)(const void*)&tokt[(size_t)ix * 512 + seg];
    const f32x4 a1 = *(const f32x4*)(const void*)&tokt[(size_t)ix * 512 + seg + 4];
    const f32x4 p0 = *(const f32x4*)(const void*)&pos[t * 512 + seg];
    const f32x4 p1 = *(const f32x4*)(const void*)&pos[t * 512 + seg + 4];
    ushort8 o;
#pragma unroll
    for (int i = 0; i < 4; i++) o[i]     = f2b(a0[i] + p0[i]);
#pragma unroll
    for (int i = 0; i < 4; i++) o[i + 4] = f2b(a1[i] + p1[i]);
    *(ushort8*)(void*)&xb[(size_t)tk * 512 + seg] = o;
}

// ---------------------------------------------------------------------------
// Weight converts (fp32 -> bf16 B^T layouts), LDS-tiled transposes
// ---------------------------------------------------------------------------
__global__ __launch_bounds__(256)
void conv_t2_k(const float* __restrict__ in, u16* __restrict__ out, int K, int N)
{
    __shared__ float t[32][33];
    const int tx = threadIdx.x & 31, ty4 = (threadIdx.x >> 5) * 4;
    const int n0 = blockIdx.x * 32, k0 = blockIdx.y * 32, l = blockIdx.z;
    const size_t per = (size_t)K * N;
    const float* src = in + l * per;
#pragma unroll
    for (int r = 0; r < 4; r++)
        t[ty4 + r][tx] = src[(size_t)(k0 + ty4 + r) * N + n0 + tx];
    __syncthreads();
    u16* dst = out + l * per;
#pragma unroll
    for (int r = 0; r < 4; r++)
        dst[(size_t)(n0 + ty4 + r) * K + k0 + tx] = f2b(t[tx][ty4 + r]);
}

__global__ __launch_bounds__(256)
void conv_qkv2_k(const float* __restrict__ wq, const float* __restrict__ wk,
                 const float* __restrict__ wv, u16* __restrict__ out)
{
    __shared__ float t[32][33];
    const int tx = threadIdx.x & 31, ty4 = (threadIdx.x >> 5) * 4;
    const int c0 = blockIdx.x * 32, d0 = blockIdx.y * 32;
    const int z = blockIdx.z;
    const int sel = z / 48, rem = z - sel * 48;
    const int l = rem >> 3, h = rem & 7;
    const float* src = (sel == 0) ? wq : (sel == 1) ? wk : wv;
    const float* sb = src + (((size_t)l * 8 + h) * 512) * 64;
#pragma unroll
    for (int r = 0; r < 4; r++)
        t[ty4 + r][tx] = sb[(size_t)(c0 + ty4 + r) * 64 + d0 + tx];
    __syncthreads();
    u16* dst = out + (size_t)l * 786432 + (size_t)(sel * 512 + h * 64 + d0) * 512;
#pragma unroll
    for (int r = 0; r < 4; r++)
        dst[(size_t)(ty4 + r) * 512 + c0 + tx] = f2b(t[tx][ty4 + r]);
}

__global__ __launch_bounds__(256)
void conv_lm_k(const float* __restrict__ lm_w, u16* __restrict__ out)
{
    int gid = blockIdx.x * 256 + threadIdx.x;
    int n = gid >> 9, c = gid & 511;
    out[gid] = (n < VOCAB) ? f2b(lm_w[(size_t)c * VOCAB + n]) : (u16)0;
}

// ---------------------------------------------------------------------------
extern "C" void kernel_launch(void* const* d_in, const int* in_sizes, int n_in,
                              void* d_out, int out_size, void* d_ws, size_t ws_size,
                              hipStream_t stream)
{
    const int*   idx    = (const int*)  d_in[0];
    const float* tokt   = (const float*)d_in[1];
    const float* post   = (const float*)d_in[2];
    const float* wq     = (const float*)d_in[3];
    const float* wk     = (const float*)d_in[4];
    const float* wvp    = (const float*)d_in[5];
    const float* proj_w = (const float*)d_in[6];
    const float* proj_b = (const float*)d_in[7];
    const float* w1     = (const float*)d_in[8];
    const float* b1     = (const float*)d_in[9];
    const float* w2     = (const float*)d_in[10];
    const float* b2     = (const float*)d_in[11];
    const float* ln1_g  = (const float*)d_in[12];
    const float* ln1_b  = (const float*)d_in[13];
    const float* ln2_g  = (const float*)d_in[14];
    const float* ln2_b  = (const float*)d_in[15];
    const float* lm_w   = (const float*)d_in[16];
    const float* lm_b   = (const float*)d_in[17];
    float* out = (float*)d_out;

    // 128 KiB dynamic LDS opt-in for the 8-phase GEMM (once per process).
    static int smem_set = 0;
    if (!smem_set) {
        smem_set = 1;
        hipFuncSetAttribute(reinterpret_cast<const void*>(&gemm256<0>),
                            hipFuncAttributeMaxDynamicSharedMemorySize, 131072);
        hipFuncSetAttribute(reinterpret_cast<const void*>(&gemm256<1>),
                            hipFuncAttributeMaxDynamicSharedMemorySize, 131072);
        hipFuncSetAttribute(reinterpret_cast<const void*>(&gemm256<2>),
                            hipFuncAttributeMaxDynamicSharedMemorySize, 131072);
    }

    char* ws = (char*)d_ws;
    u16* wqkvt = (u16*)(ws + 0);                     //  9,437,184
    u16* wprjt = (u16*)(ws + 9437184);               //  3,145,728
    u16* ww1t  = (u16*)(ws + 12582912);              // 12,582,912
    u16* ww2t  = (u16*)(ws + 25165824);              // 12,582,912
    u16* wlmt  = (u16*)(ws + 37748736);              //    131,072
    u16* xb    = (u16*)(ws + 37879808);              // 67,108,864  residual
    char* big  = ws + 104988672;                     // transient

    const size_t fixed_bytes = 104988672ull;
    const size_t avail = (ws_size > fixed_bytes) ? (ws_size - fixed_bytes) : 0;
    int chunk_a = 8192, chunk_m = 8192;
    const int cands[3] = {65536, 32768, 16384};
    for (int i = 0; i < 3; i++)
        if ((size_t)cands[i] * 3072ull <= avail) { chunk_a = cands[i]; break; }
    for (int i = 0; i < 3; i++)
        if ((size_t)cands[i] * 4096ull <= avail) { chunk_m = cands[i]; break; }
    const int nca = NTOK / chunk_a, ncm = NTOK / chunk_m;
    u16* qkvc = (u16*)big;                           // chunk_a x 1536
    u16* h1c  = (u16*)big;                           // chunk_m x 2048

    conv_qkv2_k<<<dim3(16, 2, 144), 256, 0, stream>>>(wq, wk, wvp, wqkvt);
    conv_t2_k  <<<dim3(16, 16, 6), 256, 0, stream>>>(proj_w, wprjt, 512, 512);
    conv_t2_k  <<<dim3(64, 16, 6), 256, 0, stream>>>(w1, ww1t, 512, 2048);
    conv_t2_k  <<<dim3(16, 64, 6), 256, 0, stream>>>(w2, ww2t, 2048, 512);
    conv_lm_k  <<<128 * 512 / 256, 256, 0, stream>>>(lm_w, wlmt);

    embed_k<<<NTOK * 64 / 256, 256, 0, stream>>>(idx, tokt, post, xb);

    for (int l = 0; l < NLAYER; l++) {
        // ---- attention phase ----
        for (int c = 0; c < nca; c++) {
            const size_t t0 = (size_t)c * chunk_a;
            // qkv = x @ Wqkv
            gemm256<0><<<dim3(6, chunk_a / 256), 512, 131072, stream>>>(
                xb + t0 * 512, wqkvt + (size_t)l * 786432, qkvc,
                nullptr, nullptr, 512, 512, 1536, 1536);
            // attention, in-place into q-slot of qkvc
            attn_k<<<chunk_a / 4, 256, 0, stream>>>(qkvc);
            // x = attno @ proj_w + proj_b + x   (A = q-slot, lda=1536)
            gemm256<1><<<dim3(2, chunk_a / 256), 512, 131072, stream>>>(
                qkvc, wprjt + (size_t)l * 262144, xb + t0 * 512,
                proj_b + l * 512, xb + t0 * 512, 512, 1536, 512, 512);
        }
        // x = LN1(x)  (in-place)
        ln_k<<<NTOK / 4, 256, 0, stream>>>(xb, ln1_g + l * 512, ln1_b + l * 512, xb);
        // ---- MLP phase ----
        for (int c = 0; c < ncm; c++) {
            const size_t t0 = (size_t)c * chunk_m;
            // h1 = relu(x @ w1 + b1)
            gemm256<2><<<dim3(8, chunk_m / 256), 512, 131072, stream>>>(
                xb + t0 * 512, ww1t + (size_t)l * 1048576, h1c,
                b1 + l * 2048, nullptr, 512, 512, 2048, 2048);
            // x = h1 @ w2 + b2 + x   (in-place residual)
            gemm256<1><<<dim3(2, chunk_m / 256), 512, 131072, stream>>>(
                h1c, ww2t + (size_t)l * 1048576, xb + t0 * 512,
                b2 + l * 512, xb + t0 * 512, 2048, 2048, 512, 512);
        }
        // x = LN2(x)  (in-place)
        ln_k<<<NTOK / 4, 256, 0, stream>>>(xb, ln2_g + l * 512, ln2_b + l * 512, xb);
    }

    // logits = x @ lm_w + lm_b  (N padded to 128, masked fp32 store)
    gemm_bt<3><<<dim3(1, 256), 512, 0, stream>>>(
        xb, wlmt, out, lm_b, nullptr, 512, 512, 128, VOCAB);
}